// Round 1
// baseline (322.170 us; speedup 1.0000x reference)
//
#include <hip/hip_runtime.h>
#include <hip/hip_bf16.h>

// Problem constants (fixed by the reference).
constexpr int B = 16;
constexpr int D = 256;       // feature dim
constexpr int L = 4096;      // sequence length
constexpr int N = 4096;      // queries per batch
constexpr int TS = 64;       // l-tile size for the scan
constexpr int NT = L / TS;   // 64 tiles per (b,d) row

// ---------------------------------------------------------------------------
// Kernel A: per-tile sums. One wave (64 lanes) per (row, tile); lane loads one
// float (coalesced 256B per wave), shuffle-reduce, lane0 writes partial.
// ---------------------------------------------------------------------------
__global__ __launch_bounds__(256) void tile_sums(const float* __restrict__ feat,
                                                 float* __restrict__ P) {
    int gw   = (blockIdx.x * blockDim.x + threadIdx.x) >> 6; // wave id
    int lane = threadIdx.x & 63;
    // gw in [0, B*D*NT)
    int row = gw >> 6;   // NT == 64
    int t   = gw & 63;
    float v = feat[(size_t)row * L + t * TS + lane];
    #pragma unroll
    for (int off = 32; off > 0; off >>= 1) v += __shfl_xor(v, off, 64);
    if (lane == 0) P[gw] = v;
}

// ---------------------------------------------------------------------------
// Kernel B: exclusive scan of the NT=64 tile partials per (b,d) row, in place.
// Also writes the l = L column of cs_t (total row sum). 4096 rows, 1 thr each.
// ---------------------------------------------------------------------------
__global__ __launch_bounds__(256) void scan_partials(float* __restrict__ P,
                                                     float* __restrict__ cs_t) {
    int row = blockIdx.x * blockDim.x + threadIdx.x;
    if (row >= B * D) return;
    float run = 0.f;
    #pragma unroll
    for (int t = 0; t < NT; ++t) {
        float v = P[row * NT + t];
        P[row * NT + t] = run;
        run += v;
    }
    int b = row >> 8;    // D == 256
    int d = row & 255;
    cs_t[((size_t)b * (L + 1) + L) * D + d] = run;
}

// ---------------------------------------------------------------------------
// Kernel C: per-tile local exclusive scan + transpose. Block handles a
// (b, 64-d tile, 64-l tile); loads coalesced along l, scans each d-row in LDS
// (tile[64][65]: (dd+j)%32 banking -> 2-way, free), stores coalesced along d.
// cs_t[b, l, d] = exclusive prefix sum of feat[b, d, 0..l).
// ---------------------------------------------------------------------------
__global__ __launch_bounds__(256) void transpose_scan(const float* __restrict__ feat,
                                                      const float* __restrict__ P,
                                                      float* __restrict__ cs_t) {
    __shared__ float tile[64][65];
    int bid = blockIdx.x;            // grid = B * (D/64) * NT = 4096
    int t   = bid & 63;              // l tile
    int dt  = (bid >> 6) & 3;        // d tile
    int b   = bid >> 8;
    int tid = threadIdx.x;
    int ll  = tid & 63;
    int dd0 = tid >> 6;              // 0..3
    int d0  = dt * 64;
    int l0  = t * TS;

    #pragma unroll
    for (int k = 0; k < 16; ++k) {
        int dd = dd0 + k * 4;
        tile[dd][ll] = feat[((size_t)(b * D + d0 + dd)) * L + l0 + ll];
    }
    __syncthreads();

    if (tid < 64) {
        int dd  = tid;
        int row = b * D + d0 + dd;
        float run = P[row * NT + t];     // exclusive offset of this tile
        #pragma unroll
        for (int j = 0; j < TS; ++j) {
            float v = tile[dd][j];
            tile[dd][j] = run;
            run += v;
        }
    }
    __syncthreads();

    int dd  = tid & 63;
    int ll0 = tid >> 6;
    #pragma unroll
    for (int k = 0; k < 16; ++k) {
        int l = ll0 + k * 4;
        cs_t[((size_t)b * (L + 1) + l0 + l) * D + d0 + dd] = tile[dd][l];
    }
}

// ---------------------------------------------------------------------------
// Pass 2: one wave per query. 64 lanes x float4 covers all D=256 dims in one
// instruction. 4 coalesced 1KB row reads, 3 coalesced 1KB stores per query.
//   head = cs[s+1]-cs[s]; tail = cs[e]-cs[e-1]; avg = (cs[e]-cs[s])/(e-s)
// ---------------------------------------------------------------------------
__global__ __launch_bounds__(256) void pool_queries(const float* __restrict__ cs_t,
                                                    const int* __restrict__ tois,
                                                    float* __restrict__ out) {
    int gw   = (blockIdx.x * blockDim.x + threadIdx.x) >> 6;
    int lane = threadIdx.x & 63;
    if (gw >= B * N) return;
    int b = gw >> 12;                 // N == 4096
    int s = tois[gw * 2 + 0];
    int e = tois[gw * 2 + 1];

    const size_t base = (size_t)b * (L + 1);
    const float4* r_s  = (const float4*)(cs_t + (base + s) * D);
    const float4* r_s1 = (const float4*)(cs_t + (base + s + 1) * D);
    const float4* r_e  = (const float4*)(cs_t + (base + e) * D);
    const float4* r_e1 = (const float4*)(cs_t + (base + e - 1) * D);

    float4 cs0 = r_s[lane];
    float4 cs1 = r_s1[lane];
    float4 ce0 = r_e[lane];
    float4 ce1 = r_e1[lane];

    float inv = 1.0f / (float)(e - s);
    float4 head = make_float4(cs1.x - cs0.x, cs1.y - cs0.y, cs1.z - cs0.z, cs1.w - cs0.w);
    float4 avg  = make_float4((ce0.x - cs0.x) * inv, (ce0.y - cs0.y) * inv,
                              (ce0.z - cs0.z) * inv, (ce0.w - cs0.w) * inv);
    float4 tail = make_float4(ce0.x - ce1.x, ce0.y - ce1.y, ce0.z - ce1.z, ce0.w - ce1.w);

    float* orow = out + (size_t)gw * (3 * D);
    ((float4*)orow)[lane]             = head;
    ((float4*)(orow + D))[lane]       = avg;
    ((float4*)(orow + 2 * D))[lane]   = tail;

    // counts output: (i+1)*N as float32 bit pattern (harness reads f32)
    if (gw == 0 && lane < B)
        out[(size_t)B * N * (3 * D) + lane] = (float)((lane + 1) * N);
}

// ---------------------------------------------------------------------------
// Fallback (only if ws_size is too small): direct span summation. Correct but
// uncoalesced; safety net only.
// ---------------------------------------------------------------------------
__global__ __launch_bounds__(256) void pool_direct(const float* __restrict__ feat,
                                                   const int* __restrict__ tois,
                                                   float* __restrict__ out) {
    int gw   = (blockIdx.x * blockDim.x + threadIdx.x) >> 6;
    int lane = threadIdx.x & 63;
    if (gw >= B * N) return;
    int b = gw >> 12;
    int s = tois[gw * 2 + 0];
    int e = tois[gw * 2 + 1];
    float inv = 1.0f / (float)(e - s);
    float* orow = out + (size_t)gw * (3 * D);
    #pragma unroll
    for (int c = 0; c < 4; ++c) {
        int d = c * 64 + lane;
        const float* f = feat + ((size_t)(b * D + d)) * L;
        float sum = 0.f;
        for (int j = s; j < e; ++j) sum += f[j];
        orow[d]         = f[s];
        orow[D + d]     = sum * inv;
        orow[2 * D + d] = f[e - 1];
    }
    if (gw == 0 && lane < B)
        out[(size_t)B * N * (3 * D) + lane] = (float)((lane + 1) * N);
}

extern "C" void kernel_launch(void* const* d_in, const int* in_sizes, int n_in,
                              void* d_out, int out_size, void* d_ws, size_t ws_size,
                              hipStream_t stream) {
    const float* feat = (const float*)d_in[0];
    const int*   tois = (const int*)d_in[1];
    float*       out  = (float*)d_out;

    const size_t cs_elems = (size_t)B * (L + 1) * D;      // 16,781,312
    const size_t p_elems  = (size_t)B * D * NT;           // 262,144
    const size_t need     = (cs_elems + p_elems) * sizeof(float);  // ~68.2 MB

    if (ws_size >= need) {
        float* cs_t = (float*)d_ws;
        float* P    = cs_t + cs_elems;

        // A: tile sums. waves = B*D*NT = 262144 -> 65536 blocks of 256.
        tile_sums<<<B * D * NT / 4, 256, 0, stream>>>(feat, P);
        // B: scan 64 partials per (b,d) row; writes l=L column of cs_t.
        scan_partials<<<(B * D + 255) / 256, 256, 0, stream>>>(P, cs_t);
        // C: transpose + local scan. grid = B * (D/64) * NT = 4096.
        transpose_scan<<<B * (D / 64) * NT, 256, 0, stream>>>(feat, P, cs_t);
        // Pass 2: one wave per query. 65536 waves -> 16384 blocks.
        pool_queries<<<B * N / 4, 256, 0, stream>>>(cs_t, tois, out);
    } else {
        pool_direct<<<B * N / 4, 256, 0, stream>>>(feat, tois, out);
    }
}

// Round 2
// 292.269 us; speedup vs baseline: 1.1023x; 1.1023x over previous
//
#include <hip/hip_runtime.h>
#include <hip/hip_bf16.h>

// Problem constants (fixed by the reference).
constexpr int B = 16;
constexpr int D = 256;       // feature dim
constexpr int L = 4096;      // sequence length
constexpr int N = 4096;      // queries per batch
constexpr int TS = 64;       // l-tile size for the scan
constexpr int NT = L / TS;   // 64 tiles per (b,d) row

typedef float v4f __attribute__((ext_vector_type(4)));

// ---------------------------------------------------------------------------
// K1: fused per-row tile sums + exclusive scan of tile sums.
// One block per (b,d) row (4096 blocks). float4 loads: 4 rounds x 256 thr x
// 16B = the whole 16KB row, fully coalesced. Tile (64 floats) = 16 threads ->
// segmented shfl_xor reduce. Then wave 0 shuffle-scans the 64 tile sums.
// P[row][t] = exclusive prefix of tile sums; cs_t[b][L][d] = row total.
// ---------------------------------------------------------------------------
__global__ __launch_bounds__(256) void row_scan(const float* __restrict__ feat,
                                                float* __restrict__ P,
                                                float* __restrict__ cs_t) {
    __shared__ float tsum[NT];
    int row = blockIdx.x;            // [0, B*D)
    int tid = threadIdx.x;
    const float4* fr = (const float4*)(feat + (size_t)row * L);

    float s[4];
    #pragma unroll
    for (int r = 0; r < 4; ++r) {
        float4 v = fr[r * 256 + tid];
        s[r] = (v.x + v.y) + (v.z + v.w);
    }
    #pragma unroll
    for (int r = 0; r < 4; ++r) {
        float v = s[r];
        #pragma unroll
        for (int off = 1; off < 16; off <<= 1) v += __shfl_xor(v, off, 64);
        if ((tid & 15) == 0) tsum[r * 16 + (tid >> 4)] = v;
    }
    __syncthreads();

    if (tid < NT) {
        float v = tsum[tid];
        float incl = v;
        #pragma unroll
        for (int off = 1; off < 64; off <<= 1) {
            float u = __shfl_up(incl, off, 64);
            if (tid >= off) incl += u;
        }
        P[row * NT + tid] = incl - v;            // exclusive tile offset
        if (tid == NT - 1) {                     // row total -> l = L column
            int b = row >> 8, d = row & 255;     // D == 256
            cs_t[((size_t)b * (L + 1) + L) * D + d] = incl;
        }
    }
}

// ---------------------------------------------------------------------------
// K2: per-tile exclusive scan + transpose. Block = (b, 64-d tile, 64-l tile).
// Phase 1: coalesced loads along l into LDS (pad 65 -> conflict-free).
// Phase 2: WAVE-PARALLEL scan — each of 4 waves shuffle-scans 16 rows
//          (lane j holds element j), adds the tile offset P (pre-staged in
//          LDS), writes back. No serial 64-iteration loop.
// Phase 3: coalesced stores along d.
// cs_t[b, l, d] = exclusive prefix sum of feat[b, d, 0..l).
// ---------------------------------------------------------------------------
__global__ __launch_bounds__(256) void transpose_scan(const float* __restrict__ feat,
                                                      const float* __restrict__ P,
                                                      float* __restrict__ cs_t) {
    __shared__ float tile[64][65];
    __shared__ float poff[64];
    int bid = blockIdx.x;            // grid = B * (D/64) * NT = 4096
    int t   = bid & 63;              // l tile
    int dt  = (bid >> 6) & 3;        // d tile
    int b   = bid >> 8;
    int tid = threadIdx.x;
    int ll  = tid & 63;
    int k0  = tid >> 6;              // 0..3
    int d0  = dt * 64;
    int l0  = t * TS;

    if (tid < 64) poff[tid] = P[(b * D + d0 + tid) * NT + t];
    #pragma unroll
    for (int k = 0; k < 16; ++k) {
        int dd = k0 + k * 4;
        tile[dd][ll] = feat[((size_t)(b * D + d0 + dd)) * L + l0 + ll];
    }
    __syncthreads();

    // phase 2: wave w scans rows [w*16, w*16+16)
    #pragma unroll
    for (int r = 0; r < 16; ++r) {
        int dd = k0 * 16 + r;
        float v = tile[dd][ll];
        float incl = v;
        #pragma unroll
        for (int off = 1; off < 64; off <<= 1) {
            float u = __shfl_up(incl, off, 64);
            if (ll >= off) incl += u;
        }
        tile[dd][ll] = (incl - v) + poff[dd];
    }
    __syncthreads();

    #pragma unroll
    for (int k = 0; k < 16; ++k) {
        int l = k0 + k * 4;
        cs_t[((size_t)b * (L + 1) + l0 + l) * D + d0 + ll] = tile[ll][l];
    }
}

// ---------------------------------------------------------------------------
// K3: one wave per query. Rows s/s+1 and e-1/e are CONTIGUOUS in cs_t, so we
// read two 2KB blocks instead of four scattered rows. Output (201 MB, write-
// once) goes through nontemporal stores to avoid evicting cs_t from L2/L3.
// ---------------------------------------------------------------------------
__global__ __launch_bounds__(256) void pool_queries(const float* __restrict__ cs_t,
                                                    const int* __restrict__ tois,
                                                    float* __restrict__ out) {
    int gw   = (blockIdx.x * blockDim.x + threadIdx.x) >> 6;   // query id
    int lane = threadIdx.x & 63;
    int b = gw >> 12;                 // N == 4096
    int2 se = ((const int2*)tois)[gw];
    int s = se.x, e = se.y;

    const size_t base = (size_t)b * (L + 1);
    const v4f* r_s = (const v4f*)(cs_t + (base + s) * D);
    const v4f* r_e = (const v4f*)(cs_t + (base + e) * D);

    v4f cs0 = r_s[lane];              // row s
    v4f cs1 = r_s[lane + 64];         // row s+1 (contiguous)
    v4f ce1 = r_e[lane - 64];         // row e-1 (contiguous below e)
    v4f ce0 = r_e[lane];              // row e

    float inv = 1.0f / (float)(e - s);
    v4f head = cs1 - cs0;
    v4f avg  = (ce0 - cs0) * inv;
    v4f tail = ce0 - ce1;

    v4f* orow = (v4f*)(out + (size_t)gw * (3 * D));   // 192 v4f per row
    __builtin_nontemporal_store(head, orow + lane);
    __builtin_nontemporal_store(avg,  orow + 64 + lane);
    __builtin_nontemporal_store(tail, orow + 128 + lane);

    // counts output: (i+1)*N as float32 values (harness reads f32)
    if (gw == 0 && lane < B)
        out[(size_t)B * N * (3 * D) + lane] = (float)((lane + 1) * N);
}

// ---------------------------------------------------------------------------
// Fallback (only if ws_size is too small): direct span summation.
// ---------------------------------------------------------------------------
__global__ __launch_bounds__(256) void pool_direct(const float* __restrict__ feat,
                                                   const int* __restrict__ tois,
                                                   float* __restrict__ out) {
    int gw   = (blockIdx.x * blockDim.x + threadIdx.x) >> 6;
    int lane = threadIdx.x & 63;
    if (gw >= B * N) return;
    int b = gw >> 12;
    int s = tois[gw * 2 + 0];
    int e = tois[gw * 2 + 1];
    float inv = 1.0f / (float)(e - s);
    float* orow = out + (size_t)gw * (3 * D);
    #pragma unroll
    for (int c = 0; c < 4; ++c) {
        int d = c * 64 + lane;
        const float* f = feat + ((size_t)(b * D + d)) * L;
        float sum = 0.f;
        for (int j = s; j < e; ++j) sum += f[j];
        orow[d]         = f[s];
        orow[D + d]     = sum * inv;
        orow[2 * D + d] = f[e - 1];
    }
    if (gw == 0 && lane < B)
        out[(size_t)B * N * (3 * D) + lane] = (float)((lane + 1) * N);
}

extern "C" void kernel_launch(void* const* d_in, const int* in_sizes, int n_in,
                              void* d_out, int out_size, void* d_ws, size_t ws_size,
                              hipStream_t stream) {
    const float* feat = (const float*)d_in[0];
    const int*   tois = (const int*)d_in[1];
    float*       out  = (float*)d_out;

    const size_t cs_elems = (size_t)B * (L + 1) * D;      // 16,781,312
    const size_t p_elems  = (size_t)B * D * NT;           // 262,144
    const size_t need     = (cs_elems + p_elems) * sizeof(float);  // ~68.2 MB

    if (ws_size >= need) {
        float* cs_t = (float*)d_ws;
        float* P    = cs_t + cs_elems;

        row_scan<<<B * D, 256, 0, stream>>>(feat, P, cs_t);
        transpose_scan<<<B * (D / 64) * NT, 256, 0, stream>>>(feat, P, cs_t);
        pool_queries<<<B * N / 4, 256, 0, stream>>>(cs_t, tois, out);
    } else {
        pool_direct<<<B * N / 4, 256, 0, stream>>>(feat, tois, out);
    }
}